// Round 8
// baseline (202.949 us; speedup 1.0000x reference)
//
#include <hip/hip_runtime.h>
#include <hip/hip_bf16.h>

typedef unsigned short u16;
typedef unsigned int u32;
typedef __bf16 bf16x8 __attribute__((ext_vector_type(8)));
typedef float f32x4 __attribute__((ext_vector_type(4)));

#define S_LEN 2048
#define NHEAD 16
#define HDIM  64
#define EMB   1024
#define BATCH 2

__device__ __forceinline__ float bf2f(u16 u) {
  union { unsigned int i; float f; } c; c.i = ((unsigned int)u) << 16; return c.f;
}
__device__ __forceinline__ u16 f2bf(float f) {
  union { float f; unsigned int i; } c; c.f = f;
  unsigned int i = c.i;
  return (u16)((i + 0x7FFFu + ((i >> 16) & 1u)) >> 16);
}
__device__ __forceinline__ u16 f2bf_trunc(float f) {
  union { float f; unsigned int i; } c; c.f = f;
  return (u16)(c.i >> 16);
}
__device__ __forceinline__ f32x4 mfma16(bf16x8 a, bf16x8 b, f32x4 c) {
  return __builtin_amdgcn_mfma_f32_16x16x32_bf16(a, b, c, 0, 0, 0);
}
// async global->LDS, 16B/lane; LDS dest = wave-uniform base + lane*16.
__device__ __forceinline__ void cp16(const u16* g, u16* l) {
  __builtin_amdgcn_global_load_lds(
      (const __attribute__((address_space(1))) u32*)g,
      (__attribute__((address_space(3))) u32*)l, 16, 0, 0);
}
// Counted waits + raw barrier. sched_barrier(0) ONLY at barrier points
// (m198/m201 pattern) — r3's failure was runtime buffer rotation, not this.
#define LGKM0() asm volatile("s_waitcnt lgkmcnt(0)" ::: "memory")
#define WAITVC(n) asm volatile("s_waitcnt vmcnt(" #n ")" ::: "memory")
#define SBAR() do { __builtin_amdgcn_s_barrier(); \
                    __builtin_amdgcn_sched_barrier(0); } while (0)

// Convert x (4M) + 4 weights (1M each) to bf16 (copy if already bf16).
// Per-block local dtype detect; blocks 0..255 also fill the RoPE table.
__global__ __launch_bounds__(256) void convert_kernel(
    const void* __restrict__ x, const void* __restrict__ Wq,
    const void* __restrict__ Wk, const void* __restrict__ Wv,
    const void* __restrict__ Wo,
    u16* __restrict__ xb, u16* __restrict__ wqb, u16* __restrict__ wkb,
    u16* __restrict__ wvb, u16* __restrict__ wob,
    int* __restrict__ flag, float2* __restrict__ tab)
{
  __shared__ int s_flag;
  if (threadIdx.x == 0) s_flag = 0;
  __syncthreads();
  {
    const u16* xs = (const u16*)x;
    u16 w0 = xs[threadIdx.x * 2], w1 = xs[threadIdx.x * 2 + 1];
    if ((((w0 >> 7) & 0xFF) >= 0xC0) || (((w1 >> 7) & 0xFF) >= 0xC0))
      atomicOr(&s_flag, 1);
  }
  __syncthreads();
  const int f32io = s_flag;
  if (blockIdx.x == 0 && threadIdx.x == 0) flag[0] = f32io;

  size_t gid = (size_t)blockIdx.x * 256 + threadIdx.x;
  size_t e = gid * 8;
  const void* src; u16* dst; size_t off;
  if (e < 4194304) { src = x; dst = xb; off = e; }
  else {
    size_t rr = e - 4194304;
    int j = (int)(rr >> 20); off = rr & 1048575;
    src = (j == 0) ? Wq : (j == 1) ? Wk : (j == 2) ? Wv : Wo;
    dst = (j == 0) ? wqb : (j == 1) ? wkb : (j == 2) ? wvb : wob;
  }
  if (f32io) {
    const float* s = (const float*)src + off;
    float4 a = *(const float4*)s;
    float4 b2 = *(const float4*)(s + 4);
    ushort4 u0; u0.x = f2bf(a.x); u0.y = f2bf(a.y); u0.z = f2bf(a.z); u0.w = f2bf(a.w);
    ushort4 u1; u1.x = f2bf(b2.x); u1.y = f2bf(b2.y); u1.z = f2bf(b2.z); u1.w = f2bf(b2.w);
    *(ushort4*)(dst + off) = u0;
    *(ushort4*)(dst + off + 4) = u1;
  } else {
    *(uint4*)(dst + off) = *(const uint4*)((const u16*)src + off);
  }

  if (blockIdx.x < 256) {
    int id = blockIdx.x * 256 + threadIdx.x;  // 65536 entries
    int s = id >> 5, i = id & 31;
    float f = exp2f(-(float)i * 0.41524101186092029f);  // log2(10000)/32
    float ang = (float)s * f;
    tab[id] = make_float2(cosf(ang), sinf(ang));
  }
}

// r8: deep-pipelined GEMM core, 128x128 tile, BK=32, 2 LDS buffers with
// COMPILE-TIME buffer roles (K-loop unrolled x2: halfA==buf0, halfB==buf1 —
// r3's regression came from runtime 3-buf rotation, VALUBusy x4.4).
// Depth-2 prefetch, counted vmcnt(4) (never 0 until tail): per half,
// frags(bufX) -> lgkm0+barrier (reads done) -> stage tile t+2 -> bufX ->
// MFMA -> vmcnt(4)+barrier (tile t+1 landed; t+2 stays in flight).
// Under-wait impossible: extra outstanding loads are always OLDER.
__device__ __forceinline__ void frags128(
    const u16* __restrict__ Ac, const u16* __restrict__ Bc,
    int wm, int wn, int lr, int qx, bf16x8 (&af)[4], bf16x8 (&bfr)[4])
{
#pragma unroll
  for (int mi = 0; mi < 4; ++mi)
    af[mi] = *(const bf16x8*)(Ac + (wm + mi * 16 + lr) * 32 + qx);
#pragma unroll
  for (int ni = 0; ni < 4; ++ni)
    bfr[ni] = *(const bf16x8*)(Bc + (wn + ni * 16 + lr) * 32 + qx);
}
__device__ __forceinline__ void mfma44(
    const bf16x8 (&af)[4], const bf16x8 (&bfr)[4], f32x4 (&acc)[4][4])
{
#pragma unroll
  for (int mi = 0; mi < 4; ++mi)
#pragma unroll
    for (int ni = 0; ni < 4; ++ni)
      acc[mi][ni] = mfma16(af[mi], bfr[ni], acc[mi][ni]);
}

__device__ __forceinline__ void gemm_core_dp(
    const u16* __restrict__ A, const u16* __restrict__ W,
    int m0, int n0, int t, f32x4 (&acc)[4][4],
    u16* __restrict__ Ash, u16* __restrict__ Bsh)  // each 2 bufs of 128*32
{
  const int lane = t & 63, lr = lane & 15, quad = lane >> 4;
  const int wv = t >> 6;
  const int wm = (wv & 1) * 64, wn = (wv >> 1) * 64;
  const int r0 = t >> 2;
  const int r1 = (t + 256) >> 2;
  const int c0 = (((t & 3) ^ ((t >> 2) & 3))) * 8;
  const int lds0 = (t & 192) * 8;                   // wave-uniform bases
  const int lds1 = (256 + (t & 192)) * 8;
  const int qx = ((quad ^ (lr & 3))) * 8;           // swizzled read chunk
  const u16* gA0 = A + (size_t)(m0 + r0) * 1024 + c0;
  const u16* gA1 = A + (size_t)(m0 + r1) * 1024 + c0;
  const u16* gB0 = W + (size_t)(n0 + r0) * 1024 + c0;
  const u16* gB1 = W + (size_t)(n0 + r1) * 1024 + c0;
  u16* A0 = Ash;            u16* B0 = Bsh;           // buf0
  u16* A1 = Ash + 4096;     u16* B1 = Bsh + 4096;    // buf1

#define STAGE4(kt, Ad, Bd) do { \
    cp16(gA0 + (kt), (Ad) + lds0); cp16(gA1 + (kt), (Ad) + lds1); \
    cp16(gB0 + (kt), (Bd) + lds0); cp16(gB1 + (kt), (Bd) + lds1); } while (0)

  // prologue: tile0 -> buf0, tile1 -> buf1 (depth 2)
  STAGE4(0, A0, B0);
  STAGE4(32, A1, B1);
  WAITVC(4);                 // tile0 landed; tile1 in flight
  SBAR();

  bf16x8 af[4], bfr[4];
  for (int kt = 0; kt < 960; kt += 64) {
    // ---- half A: tile kt in buf0 ----
    frags128(A0, B0, wm, wn, lr, qx, af, bfr);
    LGKM0(); SBAR();                       // all reads of buf0 retired
    STAGE4(kt + 64, A0, B0);               // tile t+2 -> buf0
    mfma44(af, bfr, acc);
    WAITVC(4); SBAR();                     // tile t+1 (buf1) landed
    // ---- half B: tile kt+32 in buf1 ----
    frags128(A1, B1, wm, wn, lr, qx, af, bfr);
    LGKM0(); SBAR();
    STAGE4(kt + 96, A1, B1);               // tile t+3 -> buf1
    mfma44(af, bfr, acc);
    WAITVC(4); SBAR();                     // tile t+2 (buf0) landed
  }
  // tail: tiles at 960 (buf0) and 992 (buf1); outstanding = 992's 4 loads
  frags128(A0, B0, wm, wn, lr, qx, af, bfr);
  mfma44(af, bfr, acc);
  WAITVC(0); SBAR();                       // tile 992 landed & visible
  frags128(A1, B1, wm, wn, lr, qx, af, bfr);
  mfma44(af, bfr, acc);
#undef STAGE4
}

__device__ __forceinline__ void gemm_epilogue(
    int mode, int f32io, f32x4 (&acc)[4][4],
    const void* biasvp, void* outvp, int m0, int n0, int t,
    const float2* __restrict__ tab)
{
  const int lane = t & 63, lr = lane & 15, quad = lane >> 4;
  const int wv = t >> 6;
  const int wm = (wv & 1) * 64, wn = (wv >> 1) * 64;
  const float* biasf = (const float*)biasvp;
  const u16* biasb = (const u16*)biasvp;
#define BIASV(n) (f32io ? biasf[(n)] : bf2f(biasb[(n)]))
  if (mode == 1) {
    u16* Out = (u16*)outvp;
#pragma unroll
    for (int mi = 0; mi < 4; ++mi) {
#pragma unroll
      for (int r = 0; r < 4; ++r) {
        int mm = m0 + wm + mi * 16 + quad * 4 + r;
        int s = mm & (S_LEN - 1), b = mm >> 11;
        float2 cs0 = tab[s * 32 + lr];
        float2 cs1 = tab[s * 32 + 16 + lr];
#pragma unroll
        for (int ni = 0; ni < 4; ++ni) {
          int n = n0 + wn + ni * 16 + lr;
          int h = n >> 6, d = n & 63;
          float v  = acc[mi][ni][r]     + BIASV(n);
          float vp = acc[mi][ni ^ 2][r] + BIASV(n ^ 32);
          float rot = (d < 32) ? -vp : vp;
          float cc = (ni & 1) ? cs1.x : cs0.x;
          float ss = (ni & 1) ? cs1.y : cs0.y;
          size_t off = (((size_t)(b * NHEAD + h)) * S_LEN + s) * HDIM + d;
          Out[off] = f2bf(v * cc + rot * ss);
        }
      }
    }
  } else if (mode == 2) {
    // V^T [bh][d][s]: the 4 r-values are consecutive s -> one 8B store.
    u16* Out = (u16*)outvp;
#pragma unroll
    for (int mi = 0; mi < 4; ++mi) {
      int mm = m0 + wm + mi * 16 + quad * 4;
      int s = mm & (S_LEN - 1), b = mm >> 11;
#pragma unroll
      for (int ni = 0; ni < 4; ++ni) {
        int n = n0 + wn + ni * 16 + lr;
        int h = n >> 6, d = n & 63;
        float bv = BIASV(n);
        u16 p0 = f2bf(acc[mi][ni][0] + bv);
        u16 p1 = f2bf(acc[mi][ni][1] + bv);
        u16 p2 = f2bf(acc[mi][ni][2] + bv);
        u16 p3 = f2bf(acc[mi][ni][3] + bv);
        uint2 pk = make_uint2((u32)p0 | ((u32)p1 << 16),
                              (u32)p2 | ((u32)p3 << 16));
        size_t off = (((size_t)(b * NHEAD + h)) * HDIM + d) * S_LEN + s;
        *(uint2*)(Out + off) = pk;
      }
    }
  }
#undef BIASV
}

// grid (24, 32) = 768 blocks. XCD-clustered remap (verified r4:
// FETCH 38->29.4 MB, dur 51->45).
__global__ __launch_bounds__(256) void gemm_qkv(
    const u16* __restrict__ A, const u16* __restrict__ Wq,
    const u16* __restrict__ Wk, const u16* __restrict__ Wv,
    const void* bq, const void* bk, const void* bv,
    u16* qo, u16* ko, u16* vo, const int* __restrict__ dflag,
    const float2* __restrict__ tab)
{
  alignas(16) __shared__ u16 Ash[2 * 128 * 32];
  alignas(16) __shared__ u16 Bsh[2 * 128 * 32];
  const int lin = blockIdx.y * 24 + blockIdx.x;   // 0..767
  const int xcd = lin & 7, rr = lin >> 3;         // rr 0..95
  const int mt = (xcd << 2) + (rr & 3);           // 0..31
  const int nw = rr >> 2;                         // 0..23
  const int wsel = nw >> 3;
  const u16* W = (wsel == 0) ? Wq : (wsel == 1) ? Wk : Wv;
  const void* bias = (wsel == 0) ? bq : (wsel == 1) ? bk : bv;
  void* out = (wsel == 0) ? (void*)qo : (wsel == 1) ? (void*)ko : (void*)vo;
  const int mode = (wsel == 2) ? 2 : 1;
  const int m0 = mt * 128, n0 = (nw & 7) * 128;
  f32x4 acc[4][4];
  const f32x4 zero4 = {0.f, 0.f, 0.f, 0.f};
#pragma unroll
  for (int i = 0; i < 4; ++i)
#pragma unroll
    for (int j = 0; j < 4; ++j) acc[i][j] = zero4;
  gemm_core_dp(A, W, m0, n0, threadIdx.x, acc, Ash, Bsh);
  gemm_epilogue(mode, dflag[0], acc, bias, out, m0, n0, threadIdx.x, tab);
}

// Output projection: 64x128 tiles, BK=32, same deep pipeline (3 loads per
// stage -> vmcnt(3)). grid (8, 64) = 512 blocks; XCD remap as r4.
__global__ __launch_bounds__(256) void gemm_out(
    const u16* __restrict__ A, const u16* __restrict__ W,
    const void* bias, void* out, const int* __restrict__ dflag)
{
  alignas(16) __shared__ u16 Ash[2 * 64 * 32];
  alignas(16) __shared__ u16 Bsh[2 * 128 * 32];
  const int t = threadIdx.x, lane = t & 63, wv = t >> 6;
  const int lr = lane & 15, quad = lane >> 4;
  const int lin = blockIdx.y * 8 + blockIdx.x;    // 0..511
  const int xcd = lin & 7, rl = lin >> 3;         // rl 0..63
  const int mt = (xcd << 3) + (rl & 7);           // 0..63
  const int m0 = mt * 64, n0 = (rl >> 3) * 128;
  const int wm = (wv & 1) * 32, wn = (wv >> 1) * 64;

  const int r0 = t >> 2;
  const int r1 = (t + 256) >> 2;
  const int c0 = (((t & 3) ^ ((t >> 2) & 3))) * 8;
  const int lds0 = (t & 192) * 8;
  const int lds1 = (256 + (t & 192)) * 8;
  const int qx = ((quad ^ (lr & 3))) * 8;
  const u16* gA0 = A + (size_t)(m0 + (r0 & 63)) * 1024 + c0;  // 256 A-chunks
  const u16* gB0 = W + (size_t)(n0 + r0) * 1024 + c0;
  const u16* gB1 = W + (size_t)(n0 + r1) * 1024 + c0;
  u16* A0 = Ash;          u16* B0 = Bsh;
  u16* A1 = Ash + 2048;   u16* B1 = Bsh + 4096;

  f32x4 acc[2][4];
  const f32x4 zero4 = {0.f, 0.f, 0.f, 0.f};
#pragma unroll
  for (int i = 0; i < 2; ++i)
#pragma unroll
    for (int j = 0; j < 4; ++j) acc[i][j] = zero4;

#define STAGE3(kt, Ad, Bd) do { \
    cp16(gA0 + (kt), (Ad) + lds0); \
    cp16(gB0 + (kt), (Bd) + lds0); cp16(gB1 + (kt), (Bd) + lds1); } while (0)
#define FRAGS2(Ac, Bc) do { \
_Pragma("unroll") \
    for (int mi = 0; mi < 2; ++mi) \
      af[mi] = *(const bf16x8*)((Ac) + (wm + mi * 16 + lr) * 32 + qx); \
_Pragma("unroll") \
    for (int ni = 0; ni < 4; ++ni) \
      bfr[ni] = *(const bf16x8*)((Bc) + (wn + ni * 16 + lr) * 32 + qx); } while (0)
#define MFMA24() do { \
_Pragma("unroll") \
    for (int mi = 0; mi < 2; ++mi) \
_Pragma("unroll") \
      for (int ni = 0; ni < 4; ++ni) \
        acc[mi][ni] = mfma16(af[mi], bfr[ni], acc[mi][ni]); } while (0)

  STAGE3(0, A0, B0);
  STAGE3(32, A1, B1);
  WAITVC(3);
  SBAR();

  bf16x8 af[2], bfr[4];
  for (int kt = 0; kt < 960; kt += 64) {
    FRAGS2(A0, B0);
    LGKM0(); SBAR();
    STAGE3(kt + 64, A0, B0);
    MFMA24();
    WAITVC(3); SBAR();
    FRAGS2(A1, B1);
    LGKM0(); SBAR();
    STAGE3(kt + 96, A1, B1);
    MFMA24();
    WAITVC(3); SBAR();
  }
  FRAGS2(A0, B0);
  MFMA24();
  WAITVC(0); SBAR();
  FRAGS2(A1, B1);
  MFMA24();
#undef STAGE3
#undef FRAGS2
#undef MFMA24

  const int f32io = dflag[0];
  const float* biasf = (const float*)bias;
  const u16* biasb = (const u16*)bias;
  float* Outf = (float*)out;
  u16* Outb = (u16*)out;
#pragma unroll
  for (int mi = 0; mi < 2; ++mi) {
#pragma unroll
    for (int r = 0; r < 4; ++r) {
      int mm = m0 + wm + mi * 16 + quad * 4 + r;
#pragma unroll
      for (int ni = 0; ni < 4; ++ni) {
        int n = n0 + wn + ni * 16 + lr;
        float bv = f32io ? biasf[n] : bf2f(biasb[n]);
        float v = acc[mi][ni][r] + bv;
        size_t off = (size_t)mm * 1024 + n;
        if (f32io) Outf[off] = v; else Outb[off] = f2bf(v);
      }
    }
  }
}

// One full QK^T -> exp -> PV phase for 16 q-rows owned by this wave
// (r7-verified): swapped QK^T; lsum on the matrix pipe via ones-B MFMA.
__device__ __forceinline__ void attn_phase(
    const bf16x8 (&qf)[2], f32x4 (&oacc)[4], f32x4& ls4,
    const u16 (*__restrict__ Ksh)[72], const u16 (*__restrict__ Vsh)[72],
    u16 (*__restrict__ Pw)[72], const bf16x8 ones,
    int kv0, int q0w, bool diag, int lr, int quad)
{
  const f32x4 zero4 = {0.f, 0.f, 0.f, 0.f};
  f32x4 sc[4];
#pragma unroll
  for (int ni = 0; ni < 4; ++ni) {
    bf16x8 kf0 = *(const bf16x8*)&Ksh[ni * 16 + lr][quad * 8];
    bf16x8 kf1 = *(const bf16x8*)&Ksh[ni * 16 + lr][32 + quad * 8];
    f32x4 z = zero4;
    z = mfma16(kf0, qf[0], z);   // K as A-operand, Q as B-operand
    z = mfma16(kf1, qf[1], z);
    sc[ni] = z;
  }
  const int qa = q0w + lr;
  if (diag) {
#pragma unroll
    for (int ni = 0; ni < 4; ++ni)
#pragma unroll
      for (int r = 0; r < 4; ++r) {
        float sarg = sc[ni][r] * 0.18033688f - 21.64042561f;
        if (kv0 + ni * 16 + quad * 4 + r > qa) sarg = -1e4f;
        sc[ni][r] = exp2f(sarg);
      }
  } else {
#pragma unroll
    for (int ni = 0; ni < 4; ++ni)
#pragma unroll
      for (int r = 0; r < 4; ++r)
        sc[ni][r] = exp2f(sc[ni][r] * 0.18033688f - 21.64042561f);
  }
#pragma unroll
  for (int ni = 0; ni < 4; ++ni) {
    u32 lo = (u32)f2bf_trunc(sc[ni][0]) | ((u32)f2bf_trunc(sc[ni][1]) << 16);
    u32 hi = (u32)f2bf_trunc(sc[ni][2]) | ((u32)f2bf_trunc(sc[ni][3]) << 16);
    *(uint2*)&Pw[lr][ni * 16 + quad * 4] = make_uint2(lo, hi);
  }
  // no barrier: Pw is wave-private; lgkmcnt orders write->read
  bf16x8 pa0 = *(const bf16x8*)&Pw[lr][quad * 8];
  bf16x8 pa1 = *(const bf16x8*)&Pw[lr][32 + quad * 8];
  ls4 = mfma16(pa0, ones, ls4);          // lsum on the matrix pipe
  ls4 = mfma16(pa1, ones, ls4);
#pragma unroll
  for (int oni = 0; oni < 4; ++oni) {
    bf16x8 vf0 = *(const bf16x8*)&Vsh[oni * 16 + lr][quad * 8];
    bf16x8 vf1 = *(const bf16x8*)&Vsh[oni * 16 + lr][32 + quad * 8];
    oacc[oni] = mfma16(pa0, vf0, oacc[oni]);
    oacc[oni] = mfma16(pa1, vf1, oacc[oni]);
  }
}

// Half-phase (kv-half `half` only) for the help-split (r7-verified).
__device__ __forceinline__ void attn_phase_half(
    const bf16x8 (&qf)[2], f32x4 (&oacc)[4], f32x4& ls4,
    const u16 (*__restrict__ Ksh)[72], const u16 (*__restrict__ Vsh)[72],
    u16 (*__restrict__ Pw)[72], const bf16x8 ones,
    int kv0, int q0w, bool diag, int half, int lr, int quad)
{
  const f32x4 zero4 = {0.f, 0.f, 0.f, 0.f};
  f32x4 sc[2];
#pragma unroll
  for (int i = 0; i < 2; ++i) {
    const int ni = half * 2 + i;
    bf16x8 kf0 = *(const bf16x8*)&Ksh[ni * 16 + lr][quad * 8];
    bf16x8 kf1 = *(const bf16x8*)&Ksh[ni * 16 + lr][32 + quad * 8];
    f32x4 z = zero4;
    z = mfma16(kf0, qf[0], z);
    z = mfma16(kf1, qf[1], z);
    sc[i] = z;
  }
  const int qa = q0w + lr;
  if (diag) {
#pragma unroll
    for (int i = 0; i < 2; ++i)
#pragma unroll
      for (int r = 0; r < 4; ++r) {
        float sarg = sc[i][r] * 0.18033688f - 21.64042561f;
        if (kv0 + (half * 2 + i) * 16 + quad * 4 + r > qa) sarg = -1e4f;
        sc[i][r] = exp2f(sarg);
      }
  } else {
#pragma unroll
    for (int i = 0; i < 2; ++i)
#pragma unroll
      for (int r = 0; r < 4; ++r)
        sc[i][r] = exp2f(sc[i][r] * 0.18033688f - 21.64042561f);
  }
#pragma unroll
  for (int i = 0; i < 2; ++i) {
    u32 lo = (u32)f2bf_trunc(sc[i][0]) | ((u32)f2bf_trunc(sc[i][1]) << 16);
    u32 hi = (u32)f2bf_trunc(sc[i][2]) | ((u32)f2bf_trunc(sc[i][3]) << 16);
    *(uint2*)&Pw[lr][(half * 2 + i) * 16 + quad * 4] = make_uint2(lo, hi);
  }
  bf16x8 pa = *(const bf16x8*)&Pw[lr][half * 32 + quad * 8];
  ls4 = mfma16(pa, ones, ls4);
#pragma unroll
  for (int oni = 0; oni < 4; ++oni) {
    bf16x8 vf = *(const bf16x8*)&Vsh[oni * 16 + lr][half * 32 + quad * 8];
    oacc[oni] = mfma16(pa, vf, oacc[oni]);
  }
}

// ls4[r] = full row-sum for q = q0w + quad*4 + r (uniform across lanes).
__device__ __forceinline__ void attn_finish(
    f32x4 (&oacc)[4], const f32x4 ls4, u16* __restrict__ O,
    int bh, int q0w, int lr, int quad)
{
  const int b = bh >> 4, h = bh & 15;
#pragma unroll
  for (int r = 0; r < 4; ++r) {
    const float scale = 1.f / ls4[r];
#pragma unroll
    for (int oni = 0; oni < 4; ++oni) {
      int s = q0w + quad * 4 + r;
      int e = h * HDIM + oni * 16 + lr;
      O[((size_t)(b * S_LEN + s)) * EMB + e] = f2bf(oacc[oni][r] * scale);
    }
  }
}

// Flash attention (r7-verified): 512-thread blocks, paired tiles with
// kv-half help-split, ones-MFMA lsum, XCD-clustered bh.
__global__ __launch_bounds__(512, 4) void attn_kernel(
    const u16* __restrict__ Q, const u16* __restrict__ Kr,
    const u16* __restrict__ Vt, u16* __restrict__ O)
{
  alignas(16) __shared__ u16 SH[27648];  // 55296 B: Kdb | Vdb | Psh
  u16 (*Kdb)[64][72] = reinterpret_cast<u16(*)[64][72]>(SH);          // [2]
  u16 (*Vdb)[64][72] = reinterpret_cast<u16(*)[64][72]>(SH + 9216);   // [2]
  u16 (*Psh)[16][72] = reinterpret_cast<u16(*)[16][72]>(SH + 18432);  // [8]
  const int t = threadIdx.x, lane = t & 63, wv = t >> 6;  // wv 0..7
  const int lr = lane & 15, quad = lane >> 4;
  const int lin = blockIdx.y * 16 + blockIdx.x;   // 0..511
  const int xcd = lin & 7, rl = lin >> 3;         // rl 0..63
  const int bh = (xcd << 2) + (rl & 3);           // 0..31
  const int qtA = rl >> 2;                        // 0..15
  const int qtB = 31 - qtA;                       // 16..31
  const bool grpA = (wv < 4);
  const int q0own = (grpA ? qtA : qtB) * 64 + (wv & 3) * 16;
  const int q0B = qtB * 64 + (wv & 3) * 16;  // partner rows for helpers
  const size_t base = (size_t)bh * S_LEN * HDIM;

  bf16x8 ones;
  {
    union { u16 u[8]; bf16x8 v; } o;
#pragma unroll
    for (int i = 0; i < 8; ++i) o.u[i] = 0x3F80;  // bf16 1.0
    ones = o.v;
  }

  bf16x8 qfO[2], qfH[2];
  {
    const u16* qrow = Q + base + (size_t)(q0own + lr) * HDIM + quad * 8;
    qfO[0] = *(const bf16x8*)qrow;
    qfO[1] = *(const bf16x8*)(qrow + 32);
  }
  if (grpA) {
    const u16* qrow = Q + base + (size_t)(q0B + lr) * HDIM + quad * 8;
    qfH[0] = *(const bf16x8*)qrow;
    qfH[1] = *(const bf16x8*)(qrow + 32);
  } else { qfH[0] = qfO[0]; qfH[1] = qfO[1]; }

  f32x4 oacc0[4], oacc1[4];
  const f32x4 zero4 = {0.f, 0.f, 0.f, 0.f};
  f32x4 ls0 = zero4, ls1 = zero4;
#pragma unroll
  for (int i = 0; i < 4; ++i) { oacc0[i] = zero4; oacc1[i] = zero4; }

  // 512 threads stage one 64x64 tile (one uint4 row-chunk each)
  const int rr = t >> 3, cc = (t & 7) * 8;
  uint4 krg = *(const uint4*)(Kr + base + (size_t)rr * HDIM + cc);
  uint4 vrg = *(const uint4*)(Vt + base + (size_t)rr * S_LEN + cc);

  for (int j = 0; j <= qtB; ++j) {
    const int cur = j & 1;
    // write buf[cur]; last readers of buf[cur] (iter j-2) finished before
    // the barrier of iter j-1 -> one barrier per iteration suffices.
    *(uint4*)&Kdb[cur][rr][cc] = krg;
    *(uint4*)&Vdb[cur][rr][cc] = vrg;
    __syncthreads();
    if (j < qtB) {
      const int kv1 = (j + 1) * 64;
      krg = *(const uint4*)(Kr + base + (size_t)(kv1 + rr) * HDIM + cc);
      vrg = *(const uint4*)(Vt + base + (size_t)rr * S_LEN + kv1 + cc);
    }
    if (j <= qtA) {
      attn_phase(qfO, oacc0, ls0, Kdb[cur], Vdb[cur], Psh[wv], ones,
                 j * 64, q0own, grpA && (j == qtA), lr, quad);
    } else if (grpA) {
      attn_phase_half(qfH, oacc1, ls1, Kdb[cur], Vdb[cur], Psh[wv], ones,
                      j * 64, q0B, j == qtB, 1, lr, quad);
    } else {
      attn_phase_half(qfO, oacc0, ls0, Kdb[cur], Vdb[cur], Psh[wv], ones,
                      j * 64, q0B, j == qtB, 0, lr, quad);
    }
  }

  // merge tile-B kv-half partials: waves 0-3 -> LDS -> waves 4-7 add.
  __syncthreads();
  float* scm = (float*)&SH[0];
  if (grpA) {
    float* dst = scm + (size_t)(wv * 64 + lane) * 21;
#pragma unroll
    for (int oni = 0; oni < 4; ++oni)
#pragma unroll
      for (int r = 0; r < 4; ++r) dst[oni * 4 + r] = oacc1[oni][r];
#pragma unroll
    for (int r = 0; r < 4; ++r) dst[16 + r] = ls1[r];
  }
  __syncthreads();
  if (!grpA) {
    const float* src = scm + (size_t)((wv - 4) * 64 + lane) * 21;
#pragma unroll
    for (int oni = 0; oni < 4; ++oni)
#pragma unroll
      for (int r = 0; r < 4; ++r) oacc0[oni][r] += src[oni * 4 + r];
#pragma unroll
    for (int r = 0; r < 4; ++r) ls0[r] += src[16 + r];
  }
  attn_finish(oacc0, ls0, O, bh, q0own, lr, quad);
}

extern "C" void kernel_launch(void* const* d_in, const int* in_sizes, int n_in,
                              void* d_out, int out_size, void* d_ws, size_t ws_size,
                              hipStream_t stream) {
  const void* x  = d_in[0];
  // d_in[1] = mask: constant causal tril, handled analytically.
  const void* Wq = d_in[2]; const void* bq = d_in[3];
  const void* Wk = d_in[4]; const void* bk = d_in[5];
  const void* Wv = d_in[6]; const void* bv = d_in[7];
  const void* Wo = d_in[8]; const void* bo = d_in[9];

  char* ws = (char*)d_ws;
  int* flag = (int*)ws;                 // 256 B
  u16* xb  = (u16*)(ws + 256);          // 4M u16
  u16* qws = xb  + 4194304;
  u16* kws = qws + 4194304;
  u16* vws = kws + 4194304;
  u16* wqb = vws + 4194304;             // 1M u16 each
  u16* wkb = wqb + 1048576;
  u16* wvb = wkb + 1048576;
  u16* wob = wvb + 1048576;
  float2* tab = (float2*)(wob + 1048576);  // 64K float2 = 512 KB
  u16* ows = xb;                        // alias: x_bf dead after QKV GEMM

  convert_kernel<<<4096, 256, 0, stream>>>(x, Wq, Wk, Wv, Wo,
                                           xb, wqb, wkb, wvb, wob, flag, tab);
  gemm_qkv<<<dim3(24, 32), 256, 0, stream>>>(xb, wqb, wkb, wvb,
                                             bq, bk, bv, qws, kws, vws, flag, tab);
  attn_kernel<<<dim3(16, 32), 512, 0, stream>>>(qws, kws, vws, ows);
  gemm_out<<<dim3(8, 64), 256, 0, stream>>>(ows, wob, bo, d_out, flag);
}

// Round 9
// 199.171 us; speedup vs baseline: 1.0190x; 1.0190x over previous
//
#include <hip/hip_runtime.h>
#include <hip/hip_bf16.h>

typedef unsigned short u16;
typedef unsigned int u32;
typedef __bf16 bf16x8 __attribute__((ext_vector_type(8)));
typedef float f32x4 __attribute__((ext_vector_type(4)));

#define S_LEN 2048
#define NHEAD 16
#define HDIM  64
#define EMB   1024
#define BATCH 2

__device__ __forceinline__ float bf2f(u16 u) {
  union { unsigned int i; float f; } c; c.i = ((unsigned int)u) << 16; return c.f;
}
__device__ __forceinline__ u16 f2bf(float f) {
  union { float f; unsigned int i; } c; c.f = f;
  unsigned int i = c.i;
  return (u16)((i + 0x7FFFu + ((i >> 16) & 1u)) >> 16);
}
__device__ __forceinline__ u16 f2bf_trunc(float f) {
  union { float f; unsigned int i; } c; c.f = f;
  return (u16)(c.i >> 16);
}
__device__ __forceinline__ f32x4 mfma16(bf16x8 a, bf16x8 b, f32x4 c) {
  return __builtin_amdgcn_mfma_f32_16x16x32_bf16(a, b, c, 0, 0, 0);
}
// async global->LDS, 16B/lane; LDS dest = wave-uniform base + lane*16,
// global source fully per-lane (guide m104/m173).
__device__ __forceinline__ void cp16(const u16* g, u16* l) {
  __builtin_amdgcn_global_load_lds(
      (const __attribute__((address_space(1))) u32*)g,
      (__attribute__((address_space(3))) u32*)l, 16, 0, 0);
}

// Convert x (4M) + 4 weights (1M each) to bf16 (copy if already bf16).
// Per-block local dtype detect; blocks 0..255 also fill the RoPE table.
__global__ __launch_bounds__(256) void convert_kernel(
    const void* __restrict__ x, const void* __restrict__ Wq,
    const void* __restrict__ Wk, const void* __restrict__ Wv,
    const void* __restrict__ Wo,
    u16* __restrict__ xb, u16* __restrict__ wqb, u16* __restrict__ wkb,
    u16* __restrict__ wvb, u16* __restrict__ wob,
    int* __restrict__ flag, float2* __restrict__ tab)
{
  __shared__ int s_flag;
  if (threadIdx.x == 0) s_flag = 0;
  __syncthreads();
  {
    const u16* xs = (const u16*)x;
    u16 w0 = xs[threadIdx.x * 2], w1 = xs[threadIdx.x * 2 + 1];
    if ((((w0 >> 7) & 0xFF) >= 0xC0) || (((w1 >> 7) & 0xFF) >= 0xC0))
      atomicOr(&s_flag, 1);
  }
  __syncthreads();
  const int f32io = s_flag;
  if (blockIdx.x == 0 && threadIdx.x == 0) flag[0] = f32io;

  size_t gid = (size_t)blockIdx.x * 256 + threadIdx.x;
  size_t e = gid * 8;
  const void* src; u16* dst; size_t off;
  if (e < 4194304) { src = x; dst = xb; off = e; }
  else {
    size_t rr = e - 4194304;
    int j = (int)(rr >> 20); off = rr & 1048575;
    src = (j == 0) ? Wq : (j == 1) ? Wk : (j == 2) ? Wv : Wo;
    dst = (j == 0) ? wqb : (j == 1) ? wkb : (j == 2) ? wvb : wob;
  }
  if (f32io) {
    const float* s = (const float*)src + off;
    float4 a = *(const float4*)s;
    float4 b2 = *(const float4*)(s + 4);
    ushort4 u0; u0.x = f2bf(a.x); u0.y = f2bf(a.y); u0.z = f2bf(a.z); u0.w = f2bf(a.w);
    ushort4 u1; u1.x = f2bf(b2.x); u1.y = f2bf(b2.y); u1.z = f2bf(b2.z); u1.w = f2bf(b2.w);
    *(ushort4*)(dst + off) = u0;
    *(ushort4*)(dst + off + 4) = u1;
  } else {
    *(uint4*)(dst + off) = *(const uint4*)((const u16*)src + off);
  }

  if (blockIdx.x < 256) {
    int id = blockIdx.x * 256 + threadIdx.x;  // 65536 entries
    int s = id >> 5, i = id & 31;
    float f = exp2f(-(float)i * 0.41524101186092029f);  // log2(10000)/32
    float ang = (float)s * f;
    tab[id] = make_float2(cosf(ang), sinf(ang));
  }
}

// Double-buffered GEMM core, 128x128 tile, BK=32, ONE barrier/iteration —
// exact r4/r7 structure (measured 44.8 us twice). r8's counted-vmcnt
// variant was null (+1.3) — regime gate: counted vmcnt only pays inside
// the 8-phase interleave, which doesn't tile for K=1024/N=3072.
__device__ __forceinline__ void gemm_core_db(
    const u16* __restrict__ A, const u16* __restrict__ W,
    int m0, int n0, int t, f32x4 (&acc)[4][4],
    u16* __restrict__ Ash, u16* __restrict__ Bsh)  // each 2 bufs of 128*32
{
  const int lane = t & 63, lr = lane & 15, quad = lane >> 4;
  const int wv = t >> 6;
  const int wm = (wv & 1) * 64, wn = (wv >> 1) * 64;
  const int r0 = t >> 2;
  const int r1 = (t + 256) >> 2;
  const int c0 = (((t & 3) ^ ((t >> 2) & 3))) * 8;
  const int lds0 = (t & 192) * 8;                   // wave-uniform bases
  const int lds1 = (256 + (t & 192)) * 8;
  const int qx = ((quad ^ (lr & 3))) * 8;           // swizzled read chunk
  const u16* gA0 = A + (size_t)(m0 + r0) * 1024 + c0;
  const u16* gA1 = A + (size_t)(m0 + r1) * 1024 + c0;
  const u16* gB0 = W + (size_t)(n0 + r0) * 1024 + c0;
  const u16* gB1 = W + (size_t)(n0 + r1) * 1024 + c0;

  // prologue: stage tile 0 into buf 0
  cp16(gA0, Ash + lds0); cp16(gA1, Ash + lds1);
  cp16(gB0, Bsh + lds0); cp16(gB1, Bsh + lds1);
  __syncthreads();

  for (int kt = 0; kt < 1024; kt += 32) {
    const int cur = (kt >> 5) & 1;
    const u16* Ac = Ash + cur * 4096;
    const u16* Bc = Bsh + cur * 4096;
    bf16x8 af[4], bfr[4];
#pragma unroll
    for (int mi = 0; mi < 4; ++mi)
      af[mi] = *(const bf16x8*)(Ac + (wm + mi * 16 + lr) * 32 + qx);
#pragma unroll
    for (int ni = 0; ni < 4; ++ni)
      bfr[ni] = *(const bf16x8*)(Bc + (wn + ni * 16 + lr) * 32 + qx);
    if (kt + 32 < 1024) {
      u16* An = Ash + (1 - cur) * 4096;
      u16* Bn = Bsh + (1 - cur) * 4096;
      cp16(gA0 + kt + 32, An + lds0); cp16(gA1 + kt + 32, An + lds1);
      cp16(gB0 + kt + 32, Bn + lds0); cp16(gB1 + kt + 32, Bn + lds1);
    }
#pragma unroll
    for (int mi = 0; mi < 4; ++mi)
#pragma unroll
      for (int ni = 0; ni < 4; ++ni)
        acc[mi][ni] = mfma16(af[mi], bfr[ni], acc[mi][ni]);
    __syncthreads();
  }
}

__device__ __forceinline__ void gemm_epilogue(
    int mode, int f32io, f32x4 (&acc)[4][4],
    const void* biasvp, void* outvp, int m0, int n0, int t,
    const float2* __restrict__ tab)
{
  const int lane = t & 63, lr = lane & 15, quad = lane >> 4;
  const int wv = t >> 6;
  const int wm = (wv & 1) * 64, wn = (wv >> 1) * 64;
  const float* biasf = (const float*)biasvp;
  const u16* biasb = (const u16*)biasvp;
#define BIASV(n) (f32io ? biasf[(n)] : bf2f(biasb[(n)]))
  if (mode == 1) {
    u16* Out = (u16*)outvp;
#pragma unroll
    for (int mi = 0; mi < 4; ++mi) {
#pragma unroll
      for (int r = 0; r < 4; ++r) {
        int mm = m0 + wm + mi * 16 + quad * 4 + r;
        int s = mm & (S_LEN - 1), b = mm >> 11;
        float2 cs0 = tab[s * 32 + lr];
        float2 cs1 = tab[s * 32 + 16 + lr];
#pragma unroll
        for (int ni = 0; ni < 4; ++ni) {
          int n = n0 + wn + ni * 16 + lr;
          int h = n >> 6, d = n & 63;
          float v  = acc[mi][ni][r]     + BIASV(n);
          float vp = acc[mi][ni ^ 2][r] + BIASV(n ^ 32);
          float rot = (d < 32) ? -vp : vp;
          float cc = (ni & 1) ? cs1.x : cs0.x;
          float ss = (ni & 1) ? cs1.y : cs0.y;
          size_t off = (((size_t)(b * NHEAD + h)) * S_LEN + s) * HDIM + d;
          Out[off] = f2bf(v * cc + rot * ss);
        }
      }
    }
  } else if (mode == 2) {
    // V^T [bh][d][s]: the 4 r-values are consecutive s -> one 8B store.
    u16* Out = (u16*)outvp;
#pragma unroll
    for (int mi = 0; mi < 4; ++mi) {
      int mm = m0 + wm + mi * 16 + quad * 4;
      int s = mm & (S_LEN - 1), b = mm >> 11;
#pragma unroll
      for (int ni = 0; ni < 4; ++ni) {
        int n = n0 + wn + ni * 16 + lr;
        int h = n >> 6, d = n & 63;
        float bv = BIASV(n);
        u16 p0 = f2bf(acc[mi][ni][0] + bv);
        u16 p1 = f2bf(acc[mi][ni][1] + bv);
        u16 p2 = f2bf(acc[mi][ni][2] + bv);
        u16 p3 = f2bf(acc[mi][ni][3] + bv);
        uint2 pk = make_uint2((u32)p0 | ((u32)p1 << 16),
                              (u32)p2 | ((u32)p3 << 16));
        size_t off = (((size_t)(b * NHEAD + h)) * HDIM + d) * S_LEN + s;
        *(uint2*)(Out + off) = pk;
      }
    }
  }
#undef BIASV
}

// grid (24, 32) = 768 blocks. XCD-clustered remap (verified r4:
// FETCH 38->29.4 MB, dur 51->45).
__global__ __launch_bounds__(256) void gemm_qkv(
    const u16* __restrict__ A, const u16* __restrict__ Wq,
    const u16* __restrict__ Wk, const u16* __restrict__ Wv,
    const void* bq, const void* bk, const void* bv,
    u16* qo, u16* ko, u16* vo, const int* __restrict__ dflag,
    const float2* __restrict__ tab)
{
  alignas(16) __shared__ u16 Ash[2 * 128 * 32];
  alignas(16) __shared__ u16 Bsh[2 * 128 * 32];
  const int lin = blockIdx.y * 24 + blockIdx.x;   // 0..767
  const int xcd = lin & 7, rr = lin >> 3;         // rr 0..95
  const int mt = (xcd << 2) + (rr & 3);           // 0..31
  const int nw = rr >> 2;                         // 0..23
  const int wsel = nw >> 3;
  const u16* W = (wsel == 0) ? Wq : (wsel == 1) ? Wk : Wv;
  const void* bias = (wsel == 0) ? bq : (wsel == 1) ? bk : bv;
  void* out = (wsel == 0) ? (void*)qo : (wsel == 1) ? (void*)ko : (void*)vo;
  const int mode = (wsel == 2) ? 2 : 1;
  const int m0 = mt * 128, n0 = (nw & 7) * 128;
  f32x4 acc[4][4];
  const f32x4 zero4 = {0.f, 0.f, 0.f, 0.f};
#pragma unroll
  for (int i = 0; i < 4; ++i)
#pragma unroll
    for (int j = 0; j < 4; ++j) acc[i][j] = zero4;
  gemm_core_db(A, W, m0, n0, threadIdx.x, acc, Ash, Bsh);
  gemm_epilogue(mode, dflag[0], acc, bias, out, m0, n0, threadIdx.x, tab);
}

// Output projection: 64x128 tiles, BK=32, double-buffered (exact r4/r7).
// grid (8, 64) = 512 blocks; XCD remap: each XCD owns 8 m-tiles.
__global__ __launch_bounds__(256) void gemm_out(
    const u16* __restrict__ A, const u16* __restrict__ W,
    const void* bias, void* out, const int* __restrict__ dflag)
{
  alignas(16) __shared__ u16 Ash[2 * 64 * 32];
  alignas(16) __shared__ u16 Bsh[2 * 128 * 32];
  const int t = threadIdx.x, lane = t & 63, wv = t >> 6;
  const int lr = lane & 15, quad = lane >> 4;
  const int lin = blockIdx.y * 8 + blockIdx.x;    // 0..511
  const int xcd = lin & 7, rl = lin >> 3;         // rl 0..63
  const int mt = (xcd << 3) + (rl & 7);           // 0..63
  const int m0 = mt * 64, n0 = (rl >> 3) * 128;
  const int wm = (wv & 1) * 32, wn = (wv >> 1) * 64;
  const int f32io = dflag[0];

  const int r0 = t >> 2;
  const int r1 = (t + 256) >> 2;
  const int c0 = (((t & 3) ^ ((t >> 2) & 3))) * 8;
  const int lds0 = (t & 192) * 8;
  const int lds1 = (256 + (t & 192)) * 8;
  const int qx = ((quad ^ (lr & 3))) * 8;
  const u16* gA0 = A + (size_t)(m0 + (r0 & 63)) * 1024 + c0;  // 256 A-chunks
  const u16* gB0 = W + (size_t)(n0 + r0) * 1024 + c0;
  const u16* gB1 = W + (size_t)(n0 + r1) * 1024 + c0;

  f32x4 acc[2][4];
  const f32x4 zero4 = {0.f, 0.f, 0.f, 0.f};
#pragma unroll
  for (int i = 0; i < 2; ++i)
#pragma unroll
    for (int j = 0; j < 4; ++j) acc[i][j] = zero4;

  cp16(gA0, Ash + lds0);
  cp16(gB0, Bsh + lds0); cp16(gB1, Bsh + lds1);
  __syncthreads();

  for (int kt = 0; kt < 1024; kt += 32) {
    const int cur = (kt >> 5) & 1;
    const u16* Ac = Ash + cur * 2048;
    const u16* Bc = Bsh + cur * 4096;
    bf16x8 af[2], bfr[4];
#pragma unroll
    for (int mi = 0; mi < 2; ++mi)
      af[mi] = *(const bf16x8*)(Ac + (wm + mi * 16 + lr) * 32 + qx);
#pragma unroll
    for (int ni = 0; ni < 4; ++ni)
      bfr[ni] = *(const bf16x8*)(Bc + (wn + ni * 16 + lr) * 32 + qx);
    if (kt + 32 < 1024) {
      u16* An = Ash + (1 - cur) * 2048;
      u16* Bn = Bsh + (1 - cur) * 4096;
      cp16(gA0 + kt + 32, An + lds0);
      cp16(gB0 + kt + 32, Bn + lds0); cp16(gB1 + kt + 32, Bn + lds1);
    }
#pragma unroll
    for (int mi = 0; mi < 2; ++mi)
#pragma unroll
      for (int ni = 0; ni < 4; ++ni)
        acc[mi][ni] = mfma16(af[mi], bfr[ni], acc[mi][ni]);
    __syncthreads();
  }

  const float* biasf = (const float*)bias;
  const u16* biasb = (const u16*)bias;
  float* Outf = (float*)out;
  u16* Outb = (u16*)out;
#pragma unroll
  for (int mi = 0; mi < 2; ++mi) {
#pragma unroll
    for (int r = 0; r < 4; ++r) {
      int mm = m0 + wm + mi * 16 + quad * 4 + r;
#pragma unroll
      for (int ni = 0; ni < 4; ++ni) {
        int n = n0 + wn + ni * 16 + lr;
        float bv = f32io ? biasf[n] : bf2f(biasb[n]);
        float v = acc[mi][ni][r] + bv;
        size_t off = (size_t)mm * 1024 + n;
        if (f32io) Outf[off] = v; else Outb[off] = f2bf(v);
      }
    }
  }
}

// One full QK^T -> exp -> PV phase (r7-verified math/layout). r9: K/V live
// in LINEAR [64][64] LDS filled by global_load_lds with 16B-chunk XOR
// swizzle pos = chunk ^ (row&7) (rule #21: inverse-swizzled SOURCE +
// swizzled READ). Read chunk offsets ck0 = (quad^(lr&7))*8,
// ck1 = ((quad+4)^(lr&7))*8 retrieve original chunks quad / quad+4.
// Bank math: row stride 128B = 0 mod 32 banks; 8 lanes per 4-bank group =
// exact b128 8-cycle floor, conflict-free.
__device__ __forceinline__ void attn_phase(
    const bf16x8 (&qf)[2], f32x4 (&oacc)[4], f32x4& ls4,
    const u16* __restrict__ Kc, const u16* __restrict__ Vc,
    u16 (*__restrict__ Pw)[72], const bf16x8 ones,
    int kv0, int q0w, bool diag, int lr, int quad, int ck0, int ck1)
{
  const f32x4 zero4 = {0.f, 0.f, 0.f, 0.f};
  f32x4 sc[4];
#pragma unroll
  for (int ni = 0; ni < 4; ++ni) {
    const u16* krow = Kc + (ni * 16 + lr) * 64;
    bf16x8 kf0 = *(const bf16x8*)(krow + ck0);
    bf16x8 kf1 = *(const bf16x8*)(krow + ck1);
    f32x4 z = zero4;
    z = mfma16(kf0, qf[0], z);   // K as A-operand, Q as B-operand
    z = mfma16(kf1, qf[1], z);
    sc[ni] = z;
  }
  const int qa = q0w + lr;
  if (diag) {
#pragma unroll
    for (int ni = 0; ni < 4; ++ni)
#pragma unroll
      for (int r = 0; r < 4; ++r) {
        float sarg = sc[ni][r] * 0.18033688f - 21.64042561f;
        if (kv0 + ni * 16 + quad * 4 + r > qa) sarg = -1e4f;
        sc[ni][r] = exp2f(sarg);
      }
  } else {
#pragma unroll
    for (int ni = 0; ni < 4; ++ni)
#pragma unroll
      for (int r = 0; r < 4; ++r)
        sc[ni][r] = exp2f(sc[ni][r] * 0.18033688f - 21.64042561f);
  }
#pragma unroll
  for (int ni = 0; ni < 4; ++ni) {
    u32 lo = (u32)f2bf_trunc(sc[ni][0]) | ((u32)f2bf_trunc(sc[ni][1]) << 16);
    u32 hi = (u32)f2bf_trunc(sc[ni][2]) | ((u32)f2bf_trunc(sc[ni][3]) << 16);
    *(uint2*)&Pw[lr][ni * 16 + quad * 4] = make_uint2(lo, hi);
  }
  // no barrier: Pw is wave-private; lgkmcnt orders write->read
  bf16x8 pa0 = *(const bf16x8*)&Pw[lr][quad * 8];
  bf16x8 pa1 = *(const bf16x8*)&Pw[lr][32 + quad * 8];
  ls4 = mfma16(pa0, ones, ls4);          // lsum on the matrix pipe
  ls4 = mfma16(pa1, ones, ls4);
#pragma unroll
  for (int oni = 0; oni < 4; ++oni) {
    const u16* vrow = Vc + (oni * 16 + lr) * 64;
    bf16x8 vf0 = *(const bf16x8*)(vrow + ck0);
    bf16x8 vf1 = *(const bf16x8*)(vrow + ck1);
    oacc[oni] = mfma16(pa0, vf0, oacc[oni]);
    oacc[oni] = mfma16(pa1, vf1, oacc[oni]);
  }
}

// Half-phase (kv-half `half` only) for the help-split (r7-verified), with
// the swizzled-chunk reads. V chunk = half*4+quad -> pos ^(lr&7).
__device__ __forceinline__ void attn_phase_half(
    const bf16x8 (&qf)[2], f32x4 (&oacc)[4], f32x4& ls4,
    const u16* __restrict__ Kc, const u16* __restrict__ Vc,
    u16 (*__restrict__ Pw)[72], const bf16x8 ones,
    int kv0, int q0w, bool diag, int half, int lr, int quad,
    int ck0, int ck1)
{
  const f32x4 zero4 = {0.f, 0.f, 0.f, 0.f};
  f32x4 sc[2];
#pragma unroll
  for (int i = 0; i < 2; ++i) {
    const int ni = half * 2 + i;
    const u16* krow = Kc + (ni * 16 + lr) * 64;
    bf16x8 kf0 = *(const bf16x8*)(krow + ck0);
    bf16x8 kf1 = *(const bf16x8*)(krow + ck1);
    f32x4 z = zero4;
    z = mfma16(kf0, qf[0], z);
    z = mfma16(kf1, qf[1], z);
    sc[i] = z;
  }
  const int qa = q0w + lr;
  if (diag) {
#pragma unroll
    for (int i = 0; i < 2; ++i)
#pragma unroll
      for (int r = 0; r < 4; ++r) {
        float sarg = sc[i][r] * 0.18033688f - 21.64042561f;
        if (kv0 + (half * 2 + i) * 16 + quad * 4 + r > qa) sarg = -1e4f;
        sc[i][r] = exp2f(sarg);
      }
  } else {
#pragma unroll
    for (int i = 0; i < 2; ++i)
#pragma unroll
      for (int r = 0; r < 4; ++r)
        sc[i][r] = exp2f(sc[i][r] * 0.18033688f - 21.64042561f);
  }
#pragma unroll
  for (int i = 0; i < 2; ++i) {
    u32 lo = (u32)f2bf_trunc(sc[i][0]) | ((u32)f2bf_trunc(sc[i][1]) << 16);
    u32 hi = (u32)f2bf_trunc(sc[i][2]) | ((u32)f2bf_trunc(sc[i][3]) << 16);
    *(uint2*)&Pw[lr][(half * 2 + i) * 16 + quad * 4] = make_uint2(lo, hi);
  }
  bf16x8 pa = *(const bf16x8*)&Pw[lr][half * 32 + quad * 8];
  ls4 = mfma16(pa, ones, ls4);
  const int ckh = ((half * 4 + quad) ^ (lr & 7)) * 8;  // s-chunk half*4+quad
#pragma unroll
  for (int oni = 0; oni < 4; ++oni) {
    bf16x8 vf = *(const bf16x8*)(Vc + (oni * 16 + lr) * 64 + ckh);
    oacc[oni] = mfma16(pa, vf, oacc[oni]);
  }
}

// ls4[r] = full row-sum for q = q0w + quad*4 + r (uniform across lanes).
__device__ __forceinline__ void attn_finish(
    f32x4 (&oacc)[4], const f32x4 ls4, u16* __restrict__ O,
    int bh, int q0w, int lr, int quad)
{
  const int b = bh >> 4, h = bh & 15;
#pragma unroll
  for (int r = 0; r < 4; ++r) {
    const float scale = 1.f / ls4[r];
#pragma unroll
    for (int oni = 0; oni < 4; ++oni) {
      int s = q0w + quad * 4 + r;
      int e = h * HDIM + oni * 16 + lr;
      O[((size_t)(b * S_LEN + s)) * EMB + e] = f2bf(oacc[oni][r] * scale);
    }
  }
}

// Flash attention (r7 structure). r9: K/V staging via global_load_lds
// (m151 pattern: DMA direct-to-LDS, no register round-trip, no ds_writes
// on the wave's issue stream). Linear [64][64] double-buffered K/V with
// 16B-chunk XOR swizzle; thread t stages dest pos t&7 of row t>>3 from
// source chunk (t&7)^(row&7); cp16 dest = wave-uniform w*1024B + lane*16.
// Issue tile j+1 right after the barrier; the NEXT barrier's vmcnt(0)
// drain lands a full phase later (~HBM latency covered).
__global__ __launch_bounds__(512, 4) void attn_kernel(
    const u16* __restrict__ Q, const u16* __restrict__ Kr,
    const u16* __restrict__ Vt, u16* __restrict__ O)
{
  alignas(16) __shared__ u16 SH[25600];  // 51200 B: K[2][4096]|V[2][4096]|P
  u16* Kbuf = SH;                        // 2 bufs x 4096 u16
  u16* Vbuf = SH + 8192;                 // 2 bufs x 4096 u16
  u16 (*Psh)[16][72] = reinterpret_cast<u16(*)[16][72]>(SH + 16384);  // [8]
  const int t = threadIdx.x, lane = t & 63, wv = t >> 6;  // wv 0..7
  const int lr = lane & 15, quad = lane >> 4;
  const int lin = blockIdx.y * 16 + blockIdx.x;   // 0..511
  const int xcd = lin & 7, rl = lin >> 3;         // rl 0..63
  const int bh = (xcd << 2) + (rl & 3);           // 0..31
  const int qtA = rl >> 2;                        // 0..15
  const int qtB = 31 - qtA;                       // 16..31
  const bool grpA = (wv < 4);
  const int q0own = (grpA ? qtA : qtB) * 64 + (wv & 3) * 16;
  const int q0B = qtB * 64 + (wv & 3) * 16;  // partner rows for helpers
  const size_t base = (size_t)bh * S_LEN * HDIM;
  const int ck0 = ((quad ^ (lr & 7))) * 8;        // swizzled chunk quad
  const int ck1 = (((quad + 4) ^ (lr & 7))) * 8;  // swizzled chunk quad+4

  // staging map: row sr = t>>3, dest pos t&7, source chunk sc = pos^(sr&7)
  const int sr = t >> 3, sc = (t & 7) ^ (sr & 7);
  const int wub = (t & 448) * 8;                  // wave-uniform dest (u16)
  const u16* gK = Kr + base + (size_t)sr * HDIM + sc * 8;
  const u16* gV = Vt + base + (size_t)sr * S_LEN + sc * 8;

  bf16x8 ones;
  {
    union { u16 u[8]; bf16x8 v; } o;
#pragma unroll
    for (int i = 0; i < 8; ++i) o.u[i] = 0x3F80;  // bf16 1.0
    ones = o.v;
  }

  bf16x8 qfO[2], qfH[2];
  {
    const u16* qrow = Q + base + (size_t)(q0own + lr) * HDIM + quad * 8;
    qfO[0] = *(const bf16x8*)qrow;
    qfO[1] = *(const bf16x8*)(qrow + 32);
  }
  if (grpA) {
    const u16* qrow = Q + base + (size_t)(q0B + lr) * HDIM + quad * 8;
    qfH[0] = *(const bf16x8*)qrow;
    qfH[1] = *(const bf16x8*)(qrow + 32);
  } else { qfH[0] = qfO[0]; qfH[1] = qfO[1]; }

  f32x4 oacc0[4], oacc1[4];
  const f32x4 zero4 = {0.f, 0.f, 0.f, 0.f};
  f32x4 ls0 = zero4, ls1 = zero4;
#pragma unroll
  for (int i = 0; i < 4; ++i) { oacc0[i] = zero4; oacc1[i] = zero4; }

  // prologue: DMA tile 0 into buf 0 (K source row = kv+sr; V col = kv+...)
  cp16(gK, Kbuf + wub);
  cp16(gV, Vbuf + wub);

  for (int j = 0; j <= qtB; ++j) {
    const int cur = j & 1;
    // barrier: (a) drains this thread's cp16 for tile j (vmcnt in the
    // __syncthreads wait) -> buf[cur] fully visible; (b) all waves have
    // finished phase j-1's reads of buf[1-cur] -> safe to refill it.
    __syncthreads();
    if (j < qtB) {
      const int kv1 = (j + 1) * 64;
      cp16(gK + (size_t)kv1 * HDIM, Kbuf + (cur ^ 1) * 4096 + wub);
      cp16(gV + kv1,                Vbuf + (cur ^ 1) * 4096 + wub);
    }
    const u16* Kc = Kbuf + cur * 4096;
    const u16* Vc = Vbuf + cur * 4096;
    if (j <= qtA) {
      attn_phase(qfO, oacc0, ls0, Kc, Vc, Psh[wv], ones,
                 j * 64, q0own, grpA && (j == qtA), lr, quad, ck0, ck1);
    } else if (grpA) {
      attn_phase_half(qfH, oacc1, ls1, Kc, Vc, Psh[wv], ones,
                      j * 64, q0B, j == qtB, 1, lr, quad, ck0, ck1);
    } else {
      attn_phase_half(qfO, oacc0, ls0, Kc, Vc, Psh[wv], ones,
                      j * 64, q0B, j == qtB, 0, lr, quad, ck0, ck1);
    }
  }

  // merge tile-B kv-half partials: waves 0-3 -> LDS -> waves 4-7 add.
  // Records: 20 floats @ stride 21 (coprime 32 -> 2-way free) in the dead
  // K/V region (256 recs x 21 x 4B = 21504 B < 32768 B K+V space).
  __syncthreads();
  float* scm = (float*)&SH[0];
  if (grpA) {
    float* dst = scm + (size_t)(wv * 64 + lane) * 21;
#pragma unroll
    for (int oni = 0; oni < 4; ++oni)
#pragma unroll
      for (int r = 0; r < 4; ++r) dst[oni * 4 + r] = oacc1[oni][r];
#pragma unroll
    for (int r = 0; r < 4; ++r) dst[16 + r] = ls1[r];
  }
  __syncthreads();
  if (!grpA) {
    const float* src = scm + (size_t)((wv - 4) * 64 + lane) * 21;
#pragma unroll
    for (int oni = 0; oni < 4; ++oni)
#pragma unroll
      for (int r = 0; r < 4; ++r) oacc0[oni][r] += src[oni * 4 + r];
#pragma unroll
    for (int r = 0; r < 4; ++r) ls0[r] += src[16 + r];
  }
  attn_finish(oacc0, ls0, O, bh, q0own, lr, quad);
}

extern "C" void kernel_launch(void* const* d_in, const int* in_sizes, int n_in,
                              void* d_out, int out_size, void* d_ws, size_t ws_size,
                              hipStream_t stream) {
  const void* x  = d_in[0];
  // d_in[1] = mask: constant causal tril, handled analytically.
  const void* Wq = d_in[2]; const void* bq = d_in[3];
  const void* Wk = d_in[4]; const void* bk = d_in[5];
  const void* Wv = d_in[6]; const void* bv = d_in[7];
  const void* Wo = d_in[8]; const void* bo = d_in[9];

  char* ws = (char*)d_ws;
  int* flag = (int*)ws;                 // 256 B
  u16* xb  = (u16*)(ws + 256);          // 4M u16
  u16* qws = xb  + 4194304;
  u16* kws = qws + 4194304;
  u16* vws = kws + 4194304;
  u16* wqb = vws + 4194304;             // 1M u16 each
  u16* wkb = wqb + 1048576;
  u16* wvb = wkb + 1048576;
  u16* wob = wvb + 1048576;
  float2* tab = (float2*)(wob + 1048576);  // 64K float2 = 512 KB
  u16* ows = xb;                        // alias: x_bf dead after QKV GEMM

  convert_kernel<<<4096, 256, 0, stream>>>(x, Wq, Wk, Wv, Wo,
                                           xb, wqb, wkb, wvb, wob, flag, tab);
  gemm_qkv<<<dim3(24, 32), 256, 0, stream>>>(xb, wqb, wkb, wvb,
                                             bq, bk, bv, qws, kws, vws, flag, tab);
  attn_kernel<<<dim3(16, 32), 512, 0, stream>>>(qws, kws, vws, ows);
  gemm_out<<<dim3(8, 64), 256, 0, stream>>>(ows, wob, bo, d_out, flag);
}

// Round 10
// 196.852 us; speedup vs baseline: 1.0310x; 1.0118x over previous
//
#include <hip/hip_runtime.h>
#include <hip/hip_bf16.h>

typedef unsigned short u16;
typedef unsigned int u32;
typedef __bf16 bf16x8 __attribute__((ext_vector_type(8)));
typedef float f32x4 __attribute__((ext_vector_type(4)));

#define S_LEN 2048
#define NHEAD 16
#define HDIM  64
#define EMB   1024
#define BATCH 2

__device__ __forceinline__ float bf2f(u16 u) {
  union { unsigned int i; float f; } c; c.i = ((unsigned int)u) << 16; return c.f;
}
__device__ __forceinline__ u16 f2bf(float f) {
  union { float f; unsigned int i; } c; c.f = f;
  unsigned int i = c.i;
  return (u16)((i + 0x7FFFu + ((i >> 16) & 1u)) >> 16);
}
__device__ __forceinline__ u16 f2bf_trunc(float f) {
  union { float f; unsigned int i; } c; c.f = f;
  return (u16)(c.i >> 16);
}
__device__ __forceinline__ f32x4 mfma16(bf16x8 a, bf16x8 b, f32x4 c) {
  return __builtin_amdgcn_mfma_f32_16x16x32_bf16(a, b, c, 0, 0, 0);
}
// async global->LDS, 16B/lane; LDS dest = wave-uniform base + lane*16,
// global source fully per-lane (guide m104/m173).
__device__ __forceinline__ void cp16(const u16* g, u16* l) {
  __builtin_amdgcn_global_load_lds(
      (const __attribute__((address_space(1))) u32*)g,
      (__attribute__((address_space(3))) u32*)l, 16, 0, 0);
}

// Convert x (4M) + 4 weights (1M each) to bf16 (copy if already bf16).
// Per-block local dtype detect; blocks 0..255 also fill the RoPE table.
__global__ __launch_bounds__(256) void convert_kernel(
    const void* __restrict__ x, const void* __restrict__ Wq,
    const void* __restrict__ Wk, const void* __restrict__ Wv,
    const void* __restrict__ Wo,
    u16* __restrict__ xb, u16* __restrict__ wqb, u16* __restrict__ wkb,
    u16* __restrict__ wvb, u16* __restrict__ wob,
    int* __restrict__ flag, float2* __restrict__ tab)
{
  __shared__ int s_flag;
  if (threadIdx.x == 0) s_flag = 0;
  __syncthreads();
  {
    const u16* xs = (const u16*)x;
    u16 w0 = xs[threadIdx.x * 2], w1 = xs[threadIdx.x * 2 + 1];
    if ((((w0 >> 7) & 0xFF) >= 0xC0) || (((w1 >> 7) & 0xFF) >= 0xC0))
      atomicOr(&s_flag, 1);
  }
  __syncthreads();
  const int f32io = s_flag;
  if (blockIdx.x == 0 && threadIdx.x == 0) flag[0] = f32io;

  size_t gid = (size_t)blockIdx.x * 256 + threadIdx.x;
  size_t e = gid * 8;
  const void* src; u16* dst; size_t off;
  if (e < 4194304) { src = x; dst = xb; off = e; }
  else {
    size_t rr = e - 4194304;
    int j = (int)(rr >> 20); off = rr & 1048575;
    src = (j == 0) ? Wq : (j == 1) ? Wk : (j == 2) ? Wv : Wo;
    dst = (j == 0) ? wqb : (j == 1) ? wkb : (j == 2) ? wvb : wob;
  }
  if (f32io) {
    const float* s = (const float*)src + off;
    float4 a = *(const float4*)s;
    float4 b2 = *(const float4*)(s + 4);
    ushort4 u0; u0.x = f2bf(a.x); u0.y = f2bf(a.y); u0.z = f2bf(a.z); u0.w = f2bf(a.w);
    ushort4 u1; u1.x = f2bf(b2.x); u1.y = f2bf(b2.y); u1.z = f2bf(b2.z); u1.w = f2bf(b2.w);
    *(ushort4*)(dst + off) = u0;
    *(ushort4*)(dst + off + 4) = u1;
  } else {
    *(uint4*)(dst + off) = *(const uint4*)((const u16*)src + off);
  }

  if (blockIdx.x < 256) {
    int id = blockIdx.x * 256 + threadIdx.x;  // 65536 entries
    int s = id >> 5, i = id & 31;
    float f = exp2f(-(float)i * 0.41524101186092029f);  // log2(10000)/32
    float ang = (float)s * f;
    tab[id] = make_float2(cosf(ang), sinf(ang));
  }
}

// Double-buffered GEMM core, 128x128 tile, BK=32, ONE barrier/iteration —
// exact r4/r7 structure (measured 44.8 us three times). r8's counted-vmcnt
// variant was null — regime gate: counted vmcnt only pays inside the
// 8-phase interleave, which doesn't tile for K=1024/N=3072.
__device__ __forceinline__ void gemm_core_db(
    const u16* __restrict__ A, const u16* __restrict__ W,
    int m0, int n0, int t, f32x4 (&acc)[4][4],
    u16* __restrict__ Ash, u16* __restrict__ Bsh)  // each 2 bufs of 128*32
{
  const int lane = t & 63, lr = lane & 15, quad = lane >> 4;
  const int wv = t >> 6;
  const int wm = (wv & 1) * 64, wn = (wv >> 1) * 64;
  const int r0 = t >> 2;
  const int r1 = (t + 256) >> 2;
  const int c0 = (((t & 3) ^ ((t >> 2) & 3))) * 8;
  const int lds0 = (t & 192) * 8;                   // wave-uniform bases
  const int lds1 = (256 + (t & 192)) * 8;
  const int qx = ((quad ^ (lr & 3))) * 8;           // swizzled read chunk
  const u16* gA0 = A + (size_t)(m0 + r0) * 1024 + c0;
  const u16* gA1 = A + (size_t)(m0 + r1) * 1024 + c0;
  const u16* gB0 = W + (size_t)(n0 + r0) * 1024 + c0;
  const u16* gB1 = W + (size_t)(n0 + r1) * 1024 + c0;

  // prologue: stage tile 0 into buf 0
  cp16(gA0, Ash + lds0); cp16(gA1, Ash + lds1);
  cp16(gB0, Bsh + lds0); cp16(gB1, Bsh + lds1);
  __syncthreads();

  for (int kt = 0; kt < 1024; kt += 32) {
    const int cur = (kt >> 5) & 1;
    const u16* Ac = Ash + cur * 4096;
    const u16* Bc = Bsh + cur * 4096;
    bf16x8 af[4], bfr[4];
#pragma unroll
    for (int mi = 0; mi < 4; ++mi)
      af[mi] = *(const bf16x8*)(Ac + (wm + mi * 16 + lr) * 32 + qx);
#pragma unroll
    for (int ni = 0; ni < 4; ++ni)
      bfr[ni] = *(const bf16x8*)(Bc + (wn + ni * 16 + lr) * 32 + qx);
    if (kt + 32 < 1024) {
      u16* An = Ash + (1 - cur) * 4096;
      u16* Bn = Bsh + (1 - cur) * 4096;
      cp16(gA0 + kt + 32, An + lds0); cp16(gA1 + kt + 32, An + lds1);
      cp16(gB0 + kt + 32, Bn + lds0); cp16(gB1 + kt + 32, Bn + lds1);
    }
#pragma unroll
    for (int mi = 0; mi < 4; ++mi)
#pragma unroll
      for (int ni = 0; ni < 4; ++ni)
        acc[mi][ni] = mfma16(af[mi], bfr[ni], acc[mi][ni]);
    __syncthreads();
  }
}

__device__ __forceinline__ void gemm_epilogue(
    int mode, int f32io, f32x4 (&acc)[4][4],
    const void* biasvp, void* outvp, int m0, int n0, int t,
    const float2* __restrict__ tab)
{
  const int lane = t & 63, lr = lane & 15, quad = lane >> 4;
  const int wv = t >> 6;
  const int wm = (wv & 1) * 64, wn = (wv >> 1) * 64;
  const float* biasf = (const float*)biasvp;
  const u16* biasb = (const u16*)biasvp;
#define BIASV(n) (f32io ? biasf[(n)] : bf2f(biasb[(n)]))
  if (mode == 1) {
    u16* Out = (u16*)outvp;
#pragma unroll
    for (int mi = 0; mi < 4; ++mi) {
#pragma unroll
      for (int r = 0; r < 4; ++r) {
        int mm = m0 + wm + mi * 16 + quad * 4 + r;
        int s = mm & (S_LEN - 1), b = mm >> 11;
        float2 cs0 = tab[s * 32 + lr];
        float2 cs1 = tab[s * 32 + 16 + lr];
#pragma unroll
        for (int ni = 0; ni < 4; ++ni) {
          int n = n0 + wn + ni * 16 + lr;
          int h = n >> 6, d = n & 63;
          float v  = acc[mi][ni][r]     + BIASV(n);
          float vp = acc[mi][ni ^ 2][r] + BIASV(n ^ 32);
          float rot = (d < 32) ? -vp : vp;
          float cc = (ni & 1) ? cs1.x : cs0.x;
          float ss = (ni & 1) ? cs1.y : cs0.y;
          size_t off = (((size_t)(b * NHEAD + h)) * S_LEN + s) * HDIM + d;
          Out[off] = f2bf(v * cc + rot * ss);
        }
      }
    }
  } else if (mode == 2) {
    // V^T [bh][d][s]: the 4 r-values are consecutive s -> one 8B store.
    u16* Out = (u16*)outvp;
#pragma unroll
    for (int mi = 0; mi < 4; ++mi) {
      int mm = m0 + wm + mi * 16 + quad * 4;
      int s = mm & (S_LEN - 1), b = mm >> 11;
#pragma unroll
      for (int ni = 0; ni < 4; ++ni) {
        int n = n0 + wn + ni * 16 + lr;
        int h = n >> 6, d = n & 63;
        float bv = BIASV(n);
        u16 p0 = f2bf(acc[mi][ni][0] + bv);
        u16 p1 = f2bf(acc[mi][ni][1] + bv);
        u16 p2 = f2bf(acc[mi][ni][2] + bv);
        u16 p3 = f2bf(acc[mi][ni][3] + bv);
        uint2 pk = make_uint2((u32)p0 | ((u32)p1 << 16),
                              (u32)p2 | ((u32)p3 << 16));
        size_t off = (((size_t)(b * NHEAD + h)) * HDIM + d) * S_LEN + s;
        *(uint2*)(Out + off) = pk;
      }
    }
  }
#undef BIASV
}

// grid (24, 32) = 768 blocks. XCD-clustered remap (verified r4:
// FETCH 38->29.4 MB, dur 51->45).
__global__ __launch_bounds__(256) void gemm_qkv(
    const u16* __restrict__ A, const u16* __restrict__ Wq,
    const u16* __restrict__ Wk, const u16* __restrict__ Wv,
    const void* bq, const void* bk, const void* bv,
    u16* qo, u16* ko, u16* vo, const int* __restrict__ dflag,
    const float2* __restrict__ tab)
{
  alignas(16) __shared__ u16 Ash[2 * 128 * 32];
  alignas(16) __shared__ u16 Bsh[2 * 128 * 32];
  const int lin = blockIdx.y * 24 + blockIdx.x;   // 0..767
  const int xcd = lin & 7, rr = lin >> 3;         // rr 0..95
  const int mt = (xcd << 2) + (rr & 3);           // 0..31
  const int nw = rr >> 2;                         // 0..23
  const int wsel = nw >> 3;
  const u16* W = (wsel == 0) ? Wq : (wsel == 1) ? Wk : Wv;
  const void* bias = (wsel == 0) ? bq : (wsel == 1) ? bk : bv;
  void* out = (wsel == 0) ? (void*)qo : (wsel == 1) ? (void*)ko : (void*)vo;
  const int mode = (wsel == 2) ? 2 : 1;
  const int m0 = mt * 128, n0 = (nw & 7) * 128;
  f32x4 acc[4][4];
  const f32x4 zero4 = {0.f, 0.f, 0.f, 0.f};
#pragma unroll
  for (int i = 0; i < 4; ++i)
#pragma unroll
    for (int j = 0; j < 4; ++j) acc[i][j] = zero4;
  gemm_core_db(A, W, m0, n0, threadIdx.x, acc, Ash, Bsh);
  gemm_epilogue(mode, dflag[0], acc, bias, out, m0, n0, threadIdx.x, tab);
}

// Output projection r10: 64x128 tiles, BK=64 -> 16 iterations (was 32).
// gemm_out runs the same latency-bound convoy per iteration as gemm_qkv
// but with half the MFMA content — its time is convoy-count-dominated, so
// halving the iteration count is the lever (m132's BK=64 regression was an
// occupancy loss; here LDS = 48KB keeps 2 blocks/CU at grid 512).
// BK=64 rows are 128B = 0 mod 32 banks -> reuse the r9-VERIFIED [row][64]
// 16B-chunk XOR swizzle (rule #21): source chunk sc = pos^(row&7), read
// chunk (ks*4+quad)^(lr&7); rows offset by multiples of 32 share sc.
// Bank math: 8 lanes per 4-bank group = exact b128 8-cyc floor.
__global__ __launch_bounds__(256) void gemm_out(
    const u16* __restrict__ A, const u16* __restrict__ W,
    const void* bias, void* out, const int* __restrict__ dflag)
{
  alignas(16) __shared__ u16 Ash[2 * 64 * 64];    // 2 bufs x 8 KB
  alignas(16) __shared__ u16 Bsh[2 * 128 * 64];   // 2 bufs x 16 KB
  const int t = threadIdx.x, lane = t & 63, wv = t >> 6;
  const int lr = lane & 15, quad = lane >> 4;
  const int lin = blockIdx.y * 8 + blockIdx.x;    // 0..511
  const int xcd = lin & 7, rl = lin >> 3;         // rl 0..63
  const int mt = (xcd << 3) + (rl & 7);           // 0..63
  const int m0 = mt * 64, n0 = (rl >> 3) * 128;
  const int wm = (wv & 1) * 32, wn = (wv >> 1) * 64;

  // staging map: row sr = t>>3 (+{0,32} A; +{0,32,64,96} B), dest pos t&7,
  // source chunk sc = (t&7)^(sr&7) (row offsets ≡ 0 mod 8 -> shared sc).
  const int sr = t >> 3, sc = (t & 7) ^ ((t >> 3) & 7);
  const int lb = (t & 192) * 8;                   // wave-uniform base (u16)
  const u16* gA0 = A + (size_t)(m0 + sr) * 1024 + sc * 8;
  const u16* gA1 = gA0 + (size_t)32 * 1024;
  const u16* gB0 = W + (size_t)(n0 + sr) * 1024 + sc * 8;
  const u16* gB1 = gB0 + (size_t)32 * 1024;
  const u16* gB2 = gB0 + (size_t)64 * 1024;
  const u16* gB3 = gB0 + (size_t)96 * 1024;

  f32x4 acc[2][4];
  const f32x4 zero4 = {0.f, 0.f, 0.f, 0.f};
#pragma unroll
  for (int i = 0; i < 2; ++i)
#pragma unroll
    for (int j = 0; j < 4; ++j) acc[i][j] = zero4;

#define STAGEO(kt, Ad, Bd) do { \
    cp16(gA0 + (kt), (Ad) + lb);        cp16(gA1 + (kt), (Ad) + 2048 + lb); \
    cp16(gB0 + (kt), (Bd) + lb);        cp16(gB1 + (kt), (Bd) + 2048 + lb); \
    cp16(gB2 + (kt), (Bd) + 4096 + lb); cp16(gB3 + (kt), (Bd) + 6144 + lb); \
  } while (0)

  // prologue: stage tile 0 into buf 0
  STAGEO(0, Ash, Bsh);
  __syncthreads();

  for (int kt = 0; kt < 1024; kt += 64) {
    const int cur = (kt >> 6) & 1;
    const u16* Ac = Ash + cur * 4096;
    const u16* Bc = Bsh + cur * 8192;
    bf16x8 af[2][2], bfr[2][4];
#pragma unroll
    for (int ks = 0; ks < 2; ++ks) {
      const int ck = ((ks * 4 + quad) ^ (lr & 7)) * 8;
#pragma unroll
      for (int mi = 0; mi < 2; ++mi)
        af[ks][mi] = *(const bf16x8*)(Ac + (wm + mi * 16 + lr) * 64 + ck);
#pragma unroll
      for (int ni = 0; ni < 4; ++ni)
        bfr[ks][ni] = *(const bf16x8*)(Bc + (wn + ni * 16 + lr) * 64 + ck);
    }
    if (kt + 64 < 1024) {
      u16* An = Ash + (1 - cur) * 4096;
      u16* Bn = Bsh + (1 - cur) * 8192;
      STAGEO(kt + 64, An, Bn);
    }
#pragma unroll
    for (int ks = 0; ks < 2; ++ks)
#pragma unroll
      for (int mi = 0; mi < 2; ++mi)
#pragma unroll
        for (int ni = 0; ni < 4; ++ni)
          acc[mi][ni] = mfma16(af[ks][mi], bfr[ks][ni], acc[mi][ni]);
    __syncthreads();
  }
#undef STAGEO

  const int f32io = dflag[0];
  const float* biasf = (const float*)bias;
  const u16* biasb = (const u16*)bias;
  float* Outf = (float*)out;
  u16* Outb = (u16*)out;
#pragma unroll
  for (int mi = 0; mi < 2; ++mi) {
#pragma unroll
    for (int r = 0; r < 4; ++r) {
      int mm = m0 + wm + mi * 16 + quad * 4 + r;
#pragma unroll
      for (int ni = 0; ni < 4; ++ni) {
        int n = n0 + wn + ni * 16 + lr;
        float bv = f32io ? biasf[n] : bf2f(biasb[n]);
        float v = acc[mi][ni][r] + bv;
        size_t off = (size_t)mm * 1024 + n;
        if (f32io) Outf[off] = v; else Outb[off] = f2bf(v);
      }
    }
  }
}

// One full QK^T -> exp -> PV phase (r7-verified math/layout; r9-verified
// LDS scheme). K/V live in LINEAR [64][64] LDS filled by global_load_lds
// with 16B-chunk XOR swizzle pos = chunk ^ (row&7); read chunk offsets
// ck0/ck1 retrieve original chunks quad / quad+4. Conflict-free (8 lanes
// per 4-bank group = b128 floor).
__device__ __forceinline__ void attn_phase(
    const bf16x8 (&qf)[2], f32x4 (&oacc)[4], f32x4& ls4,
    const u16* __restrict__ Kc, const u16* __restrict__ Vc,
    u16 (*__restrict__ Pw)[72], const bf16x8 ones,
    int kv0, int q0w, bool diag, int lr, int quad, int ck0, int ck1)
{
  const f32x4 zero4 = {0.f, 0.f, 0.f, 0.f};
  f32x4 sc[4];
#pragma unroll
  for (int ni = 0; ni < 4; ++ni) {
    const u16* krow = Kc + (ni * 16 + lr) * 64;
    bf16x8 kf0 = *(const bf16x8*)(krow + ck0);
    bf16x8 kf1 = *(const bf16x8*)(krow + ck1);
    f32x4 z = zero4;
    z = mfma16(kf0, qf[0], z);   // K as A-operand, Q as B-operand
    z = mfma16(kf1, qf[1], z);
    sc[ni] = z;
  }
  const int qa = q0w + lr;
  if (diag) {
#pragma unroll
    for (int ni = 0; ni < 4; ++ni)
#pragma unroll
      for (int r = 0; r < 4; ++r) {
        float sarg = sc[ni][r] * 0.18033688f - 21.64042561f;
        if (kv0 + ni * 16 + quad * 4 + r > qa) sarg = -1e4f;
        sc[ni][r] = exp2f(sarg);
      }
  } else {
#pragma unroll
    for (int ni = 0; ni < 4; ++ni)
#pragma unroll
      for (int r = 0; r < 4; ++r)
        sc[ni][r] = exp2f(sc[ni][r] * 0.18033688f - 21.64042561f);
  }
#pragma unroll
  for (int ni = 0; ni < 4; ++ni) {
    u32 lo = (u32)f2bf_trunc(sc[ni][0]) | ((u32)f2bf_trunc(sc[ni][1]) << 16);
    u32 hi = (u32)f2bf_trunc(sc[ni][2]) | ((u32)f2bf_trunc(sc[ni][3]) << 16);
    *(uint2*)&Pw[lr][ni * 16 + quad * 4] = make_uint2(lo, hi);
  }
  // no barrier: Pw is wave-private; lgkmcnt orders write->read
  bf16x8 pa0 = *(const bf16x8*)&Pw[lr][quad * 8];
  bf16x8 pa1 = *(const bf16x8*)&Pw[lr][32 + quad * 8];
  ls4 = mfma16(pa0, ones, ls4);          // lsum on the matrix pipe
  ls4 = mfma16(pa1, ones, ls4);
#pragma unroll
  for (int oni = 0; oni < 4; ++oni) {
    const u16* vrow = Vc + (oni * 16 + lr) * 64;
    bf16x8 vf0 = *(const bf16x8*)(vrow + ck0);
    bf16x8 vf1 = *(const bf16x8*)(vrow + ck1);
    oacc[oni] = mfma16(pa0, vf0, oacc[oni]);
    oacc[oni] = mfma16(pa1, vf1, oacc[oni]);
  }
}

// Half-phase (kv-half `half` only) for the help-split (r7/r9-verified).
__device__ __forceinline__ void attn_phase_half(
    const bf16x8 (&qf)[2], f32x4 (&oacc)[4], f32x4& ls4,
    const u16* __restrict__ Kc, const u16* __restrict__ Vc,
    u16 (*__restrict__ Pw)[72], const bf16x8 ones,
    int kv0, int q0w, bool diag, int half, int lr, int quad,
    int ck0, int ck1)
{
  const f32x4 zero4 = {0.f, 0.f, 0.f, 0.f};
  f32x4 sc[2];
#pragma unroll
  for (int i = 0; i < 2; ++i) {
    const int ni = half * 2 + i;
    const u16* krow = Kc + (ni * 16 + lr) * 64;
    bf16x8 kf0 = *(const bf16x8*)(krow + ck0);
    bf16x8 kf1 = *(const bf16x8*)(krow + ck1);
    f32x4 z = zero4;
    z = mfma16(kf0, qf[0], z);
    z = mfma16(kf1, qf[1], z);
    sc[i] = z;
  }
  const int qa = q0w + lr;
  if (diag) {
#pragma unroll
    for (int i = 0; i < 2; ++i)
#pragma unroll
      for (int r = 0; r < 4; ++r) {
        float sarg = sc[i][r] * 0.18033688f - 21.64042561f;
        if (kv0 + (half * 2 + i) * 16 + quad * 4 + r > qa) sarg = -1e4f;
        sc[i][r] = exp2f(sarg);
      }
  } else {
#pragma unroll
    for (int i = 0; i < 2; ++i)
#pragma unroll
      for (int r = 0; r < 4; ++r)
        sc[i][r] = exp2f(sc[i][r] * 0.18033688f - 21.64042561f);
  }
#pragma unroll
  for (int i = 0; i < 2; ++i) {
    u32 lo = (u32)f2bf_trunc(sc[i][0]) | ((u32)f2bf_trunc(sc[i][1]) << 16);
    u32 hi = (u32)f2bf_trunc(sc[i][2]) | ((u32)f2bf_trunc(sc[i][3]) << 16);
    *(uint2*)&Pw[lr][(half * 2 + i) * 16 + quad * 4] = make_uint2(lo, hi);
  }
  bf16x8 pa = *(const bf16x8*)&Pw[lr][half * 32 + quad * 8];
  ls4 = mfma16(pa, ones, ls4);
  const int ckh = ((half * 4 + quad) ^ (lr & 7)) * 8;  // s-chunk half*4+quad
#pragma unroll
  for (int oni = 0; oni < 4; ++oni) {
    bf16x8 vf = *(const bf16x8*)(Vc + (oni * 16 + lr) * 64 + ckh);
    oacc[oni] = mfma16(pa, vf, oacc[oni]);
  }
}

// ls4[r] = full row-sum for q = q0w + quad*4 + r (uniform across lanes).
__device__ __forceinline__ void attn_finish(
    f32x4 (&oacc)[4], const f32x4 ls4, u16* __restrict__ O,
    int bh, int q0w, int lr, int quad)
{
  const int b = bh >> 4, h = bh & 15;
#pragma unroll
  for (int r = 0; r < 4; ++r) {
    const float scale = 1.f / ls4[r];
#pragma unroll
    for (int oni = 0; oni < 4; ++oni) {
      int s = q0w + quad * 4 + r;
      int e = h * HDIM + oni * 16 + lr;
      O[((size_t)(b * S_LEN + s)) * EMB + e] = f2bf(oacc[oni][r] * scale);
    }
  }
}

// Flash attention (r9-verified): global_load_lds K/V staging (linear
// [64][64] double-buffered, 16B-chunk XOR swizzle), paired tiles with
// kv-half help-split, ones-MFMA lsum, XCD-clustered bh.
__global__ __launch_bounds__(512, 4) void attn_kernel(
    const u16* __restrict__ Q, const u16* __restrict__ Kr,
    const u16* __restrict__ Vt, u16* __restrict__ O)
{
  alignas(16) __shared__ u16 SH[25600];  // 51200 B: K[2][4096]|V[2][4096]|P
  u16* Kbuf = SH;                        // 2 bufs x 4096 u16
  u16* Vbuf = SH + 8192;                 // 2 bufs x 4096 u16
  u16 (*Psh)[16][72] = reinterpret_cast<u16(*)[16][72]>(SH + 16384);  // [8]
  const int t = threadIdx.x, lane = t & 63, wv = t >> 6;  // wv 0..7
  const int lr = lane & 15, quad = lane >> 4;
  const int lin = blockIdx.y * 16 + blockIdx.x;   // 0..511
  const int xcd = lin & 7, rl = lin >> 3;         // rl 0..63
  const int bh = (xcd << 2) + (rl & 3);           // 0..31
  const int qtA = rl >> 2;                        // 0..15
  const int qtB = 31 - qtA;                       // 16..31
  const bool grpA = (wv < 4);
  const int q0own = (grpA ? qtA : qtB) * 64 + (wv & 3) * 16;
  const int q0B = qtB * 64 + (wv & 3) * 16;  // partner rows for helpers
  const size_t base = (size_t)bh * S_LEN * HDIM;
  const int ck0 = ((quad ^ (lr & 7))) * 8;        // swizzled chunk quad
  const int ck1 = (((quad + 4) ^ (lr & 7))) * 8;  // swizzled chunk quad+4

  // staging map: row sr = t>>3, dest pos t&7, source chunk sc = pos^(sr&7)
  const int sr = t >> 3, sc = (t & 7) ^ (sr & 7);
  const int wub = (t & 448) * 8;                  // wave-uniform dest (u16)
  const u16* gK = Kr + base + (size_t)sr * HDIM + sc * 8;
  const u16* gV = Vt + base + (size_t)sr * S_LEN + sc * 8;

  bf16x8 ones;
  {
    union { u16 u[8]; bf16x8 v; } o;
#pragma unroll
    for (int i = 0; i < 8; ++i) o.u[i] = 0x3F80;  // bf16 1.0
    ones = o.v;
  }

  bf16x8 qfO[2], qfH[2];
  {
    const u16* qrow = Q + base + (size_t)(q0own + lr) * HDIM + quad * 8;
    qfO[0] = *(const bf16x8*)qrow;
    qfO[1] = *(const bf16x8*)(qrow + 32);
  }
  if (grpA) {
    const u16* qrow = Q + base + (size_t)(q0B + lr) * HDIM + quad * 8;
    qfH[0] = *(const bf16x8*)qrow;
    qfH[1] = *(const bf16x8*)(qrow + 32);
  } else { qfH[0] = qfO[0]; qfH[1] = qfO[1]; }

  f32x4 oacc0[4], oacc1[4];
  const f32x4 zero4 = {0.f, 0.f, 0.f, 0.f};
  f32x4 ls0 = zero4, ls1 = zero4;
#pragma unroll
  for (int i = 0; i < 4; ++i) { oacc0[i] = zero4; oacc1[i] = zero4; }

  // prologue: DMA tile 0 into buf 0
  cp16(gK, Kbuf + wub);
  cp16(gV, Vbuf + wub);

  for (int j = 0; j <= qtB; ++j) {
    const int cur = j & 1;
    // barrier: (a) drains this thread's cp16 for tile j (vmcnt in the
    // __syncthreads wait) -> buf[cur] fully visible; (b) all waves have
    // finished phase j-1's reads of buf[1-cur] -> safe to refill it.
    __syncthreads();
    if (j < qtB) {
      const int kv1 = (j + 1) * 64;
      cp16(gK + (size_t)kv1 * HDIM, Kbuf + (cur ^ 1) * 4096 + wub);
      cp16(gV + kv1,                Vbuf + (cur ^ 1) * 4096 + wub);
    }
    const u16* Kc = Kbuf + cur * 4096;
    const u16* Vc = Vbuf + cur * 4096;
    if (j <= qtA) {
      attn_phase(qfO, oacc0, ls0, Kc, Vc, Psh[wv], ones,
                 j * 64, q0own, grpA && (j == qtA), lr, quad, ck0, ck1);
    } else if (grpA) {
      attn_phase_half(qfH, oacc1, ls1, Kc, Vc, Psh[wv], ones,
                      j * 64, q0B, j == qtB, 1, lr, quad, ck0, ck1);
    } else {
      attn_phase_half(qfO, oacc0, ls0, Kc, Vc, Psh[wv], ones,
                      j * 64, q0B, j == qtB, 0, lr, quad, ck0, ck1);
    }
  }

  // merge tile-B kv-half partials: waves 0-3 -> LDS -> waves 4-7 add.
  // Records: 20 floats @ stride 21 (coprime 32 -> 2-way free) in the dead
  // K/V region (256 recs x 21 x 4B = 21504 B < 32768 B K+V space).
  __syncthreads();
  float* scm = (float*)&SH[0];
  if (grpA) {
    float* dst = scm + (size_t)(wv * 64 + lane) * 21;
#pragma unroll
    for (int oni = 0; oni < 4; ++oni)
#pragma unroll
      for (int r = 0; r < 4; ++r) dst[oni * 4 + r] = oacc1[oni][r];
#pragma unroll
    for (int r = 0; r < 4; ++r) dst[16 + r] = ls1[r];
  }
  __syncthreads();
  if (!grpA) {
    const float* src = scm + (size_t)((wv - 4) * 64 + lane) * 21;
#pragma unroll
    for (int oni = 0; oni < 4; ++oni)
#pragma unroll
      for (int r = 0; r < 4; ++r) oacc0[oni][r] += src[oni * 4 + r];
#pragma unroll
    for (int r = 0; r < 4; ++r) ls0[r] += src[16 + r];
  }
  attn_finish(oacc0, ls0, O, bh, q0own, lr, quad);
}

extern "C" void kernel_launch(void* const* d_in, const int* in_sizes, int n_in,
                              void* d_out, int out_size, void* d_ws, size_t ws_size,
                              hipStream_t stream) {
  const void* x  = d_in[0];
  // d_in[1] = mask: constant causal tril, handled analytically.
  const void* Wq = d_in[2]; const void* bq = d_in[3];
  const void* Wk = d_in[4]; const void* bk = d_in[5];
  const void* Wv = d_in[6]; const void* bv = d_in[7];
  const void* Wo = d_in[8]; const void* bo = d_in[9];

  char* ws = (char*)d_ws;
  int* flag = (int*)ws;                 // 256 B
  u16* xb  = (u16*)(ws + 256);          // 4M u16
  u16* qws = xb  + 4194304;
  u16* kws = qws + 4194304;
  u16* vws = kws + 4194304;
  u16* wqb = vws + 4194304;             // 1M u16 each
  u16* wkb = wqb + 1048576;
  u16* wvb = wkb + 1048576;
  u16* wob = wvb + 1048576;
  float2* tab = (float2*)(wob + 1048576);  // 64K float2 = 512 KB
  u16* ows = xb;                        // alias: x_bf dead after QKV GEMM

  convert_kernel<<<4096, 256, 0, stream>>>(x, Wq, Wk, Wv, Wo,
                                           xb, wqb, wkb, wvb, wob, flag, tab);
  gemm_qkv<<<dim3(24, 32), 256, 0, stream>>>(xb, wqb, wkb, wvb,
                                             bq, bk, bv, qws, kws, vws, flag, tab);
  attn_kernel<<<dim3(16, 32), 512, 0, stream>>>(qws, kws, vws, ows);
  gemm_out<<<dim3(8, 64), 256, 0, stream>>>(ows, wob, bo, d_out, flag);
}